// Round 3
// baseline (240.623 us; speedup 1.0000x reference)
//
#include <hip/hip_runtime.h>

typedef __bf16   bf16x8 __attribute__((ext_vector_type(8)));
typedef float    f32x4  __attribute__((ext_vector_type(4)));
typedef float    f32x2  __attribute__((ext_vector_type(2)));
typedef uint32_t u32x4  __attribute__((ext_vector_type(4)));

constexpr int N_ = 16384;
constexpr int D_ = 16;
constexpr int P_ = 8;
constexpr int H_ = 128;
constexpr int M_ = 50;

// pack two f32 -> one bf16x2 register word (round-half-up; 3 VALU ops)
__device__ __forceinline__ uint32_t pk_bf16(float a, float b) {
    uint32_t ua = __builtin_bit_cast(uint32_t, a) + 0x8000u;
    uint32_t ub = __builtin_bit_cast(uint32_t, b) + 0x8000u;
    return __builtin_amdgcn_perm(ub, ua, 0x07060302u);   // [a.hi16 | b.hi16]
}
__device__ __forceinline__ uint32_t pk_relu_bf16(float a, float b) {
    return pk_bf16(fmaxf(a, 0.0f), fmaxf(b, 0.0f));
}

// R6: TIME-SPLIT parallelism. Key structural fact: X_{m+1}=0.98*X_m+sqdt*eps_m
// does not depend on the network output Z; V is a plain sum of per-step
// contributions. So the 50 network evaluations are mutually independent given
// the (2-op) X recurrence. Each block = 2 waves on the SAME 16 particles:
//   wave 0: evaluates steps  0..24
//   wave 1: replays the cheap X recurrence for 0..24, then evaluates 25..49
// NO barriers in the main loop (the R4 lesson: barrier-locked waves can't
// overlap); one __syncthreads at the end to combine V partials via 64B LDS.
// Each wave keeps the full R0 register-resident structure (all 8 ct tiles,
// 8 independent L2 chains, ~152 VGPR -> 2 waves/SIMD).
__global__ __launch_bounds__(128, 2)
void sde_fused(const float* __restrict__ X0,
               const float* __restrict__ V0,
               const float* __restrict__ Yobs,
               const float* __restrict__ noise,
               const float* __restrict__ W1, const float* __restrict__ b1,
               const float* __restrict__ W2, const float* __restrict__ b2,
               const float* __restrict__ W3, const float* __restrict__ b3,
               float* __restrict__ out)
{
    const int tid  = threadIdx.x;
    const int lane = tid & 63;
    const int half = tid >> 6;           // 0: steps 0..24, 1: steps 25..49
    const int n    = lane & 15;
    const int q    = lane >> 4;
    const int gr   = blockIdx.x * 16 + n;

    const float dt   = 0.02f;
    const float sqdt = 0.1414213562373095f;

    // ---- weight fragments, A-operand layout A[m=lane&15][k=q*8+j] ----
    bf16x8 w1f[8];
#pragma unroll
    for (int ct = 0; ct < 8; ++ct) {
        u32x4 u;
        u[0] = pk_bf16(W1[(1 + q * 4 + 0) * H_ + ct * 16 + n],
                       W1[(1 + q * 4 + 1) * H_ + ct * 16 + n]);
        u[1] = pk_bf16(W1[(1 + q * 4 + 2) * H_ + ct * 16 + n],
                       W1[(1 + q * 4 + 3) * H_ + ct * 16 + n]);
        u[2] = pk_bf16(W1[(17 + q * 2 + 0) * H_ + ct * 16 + n],
                       W1[(17 + q * 2 + 1) * H_ + ct * 16 + n]);
        u[3] = (q == 0) ? pk_bf16(b1[ct * 16 + n], W1[ct * 16 + n]) : 0u;
        w1f[ct] = __builtin_bit_cast(bf16x8, u);
    }
    bf16x8 w2f[8][4];
#pragma unroll
    for (int ct = 0; ct < 8; ++ct)
#pragma unroll
        for (int kt = 0; kt < 4; ++kt) {
            u32x4 u;
#pragma unroll
            for (int w = 0; w < 4; ++w) {
                int h0 = (kt * 2 + (w >> 1)) * 16 + q * 4 + (w & 1) * 2;
                u[w] = pk_bf16(W2[h0 * H_ + ct * 16 + n],
                               W2[(h0 + 1) * H_ + ct * 16 + n]);
            }
            w2f[ct][kt] = __builtin_bit_cast(bf16x8, u);
        }
    bf16x8 w3f[4];
#pragma unroll
    for (int kt = 0; kt < 4; ++kt) {
        u32x4 u;
#pragma unroll
        for (int w = 0; w < 4; ++w) {
            int h0 = (kt * 2 + (w >> 1)) * 16 + q * 4 + (w & 1) * 2;
            u[w] = pk_bf16(W3[h0 * D_ + n], W3[(h0 + 1) * D_ + n]);
        }
        w3f[kt] = __builtin_bit_cast(bf16x8, u);
    }
    f32x4 b2r[8];
#pragma unroll
    for (int ct = 0; ct < 8; ++ct)
#pragma unroll
        for (int r = 0; r < 4; ++r) b2r[ct][r] = b2[ct * 16 + q * 4 + r];
    f32x4 b3r;
#pragma unroll
    for (int r = 0; r < 4; ++r) b3r[r] = b3[q * 4 + r];

    // ---- state ----
    f32x4 x = *(const f32x4*)&X0[gr * D_ + q * 4];
    f32x2 y2 = *(const f32x2*)&Yobs[gr * P_ + q * 2];
    const uint32_t yw = pk_bf16(y2[0], y2[1]);   // constant word2 of a0

    const float* npb = noise + (size_t)gr * D_ + q * 4;

    // ---- wave 1: replay the X recurrence through steps 0..24 ----
    // Bit-identical ops to wave 0's in-loop update, so x matches exactly at
    // the handoff. Moderate unroll: overlap the (cached) noise loads without
    // spiking register pressure on top of the resident weights.
    if (half == 1) {
#pragma unroll 5
        for (int m = 0; m < 25; ++m) {
            f32x4 e = *(const f32x4*)(npb + (size_t)m * N_ * D_);
#pragma unroll
            for (int r = 0; r < 4; ++r)
                x[r] = fmaf(x[r], 0.98f, sqdt * e[r]);
        }
    }

    const int s0 = half * 25;            // own step window: [s0, s0+25)
    float t = half ? 0.5f : 0.0f;        // 25*dt = 0.5 exactly

    f32x4 e0 = *(const f32x4*)(npb + (size_t)s0 * N_ * D_);
    f32x4 e1 = *(const f32x4*)(npb + (size_t)(s0 + 1) * N_ * D_);
    float vacc = 0.0f;   // per-lane V partial, reduced once after the loop

    for (int i = 0; i < 25; ++i) {
        const int m  = s0 + i;
        const int mp = (m + 2 < M_) ? (m + 2) : (M_ - 1);
        f32x4 e2 = *(const f32x4*)(npb + (size_t)mp * N_ * D_);

        // ---- layer 1 B fragment: [X(4) | Y(2) | one | t] ----
        u32x4 au;
        au[0] = pk_bf16(x[0], x[1]);
        au[1] = pk_bf16(x[2], x[3]);
        au[2] = yw;
        au[3] = (q == 0) ? pk_bf16(1.0f, t) : 0u;
        bf16x8 a0 = __builtin_bit_cast(bf16x8, au);

        f32x4 h1c[8];
#pragma unroll
        for (int ct = 0; ct < 8; ++ct)
            h1c[ct] = __builtin_amdgcn_mfma_f32_16x16x32_bf16(
                w1f[ct], a0, (f32x4){0.f, 0.f, 0.f, 0.f}, 0, 0, 0);

        bf16x8 h1b[4];
#pragma unroll
        for (int kt = 0; kt < 4; ++kt) {
            u32x4 u;
            u[0] = pk_relu_bf16(h1c[2 * kt][0], h1c[2 * kt][1]);
            u[1] = pk_relu_bf16(h1c[2 * kt][2], h1c[2 * kt][3]);
            u[2] = pk_relu_bf16(h1c[2 * kt + 1][0], h1c[2 * kt + 1][1]);
            u[3] = pk_relu_bf16(h1c[2 * kt + 1][2], h1c[2 * kt + 1][3]);
            h1b[kt] = __builtin_bit_cast(bf16x8, u);
        }

        // ---- layer 2: 8 independent chains of 4 ----
        f32x4 h2c[8];
#pragma unroll
        for (int ct = 0; ct < 8; ++ct) {
            f32x4 c = b2r[ct];
#pragma unroll
            for (int kt = 0; kt < 4; ++kt)
                c = __builtin_amdgcn_mfma_f32_16x16x32_bf16(w2f[ct][kt], h1b[kt], c, 0, 0, 0);
            h2c[ct] = c;
        }
        bf16x8 h2b[4];
#pragma unroll
        for (int kt = 0; kt < 4; ++kt) {
            u32x4 u;
            u[0] = pk_relu_bf16(h2c[2 * kt][0], h2c[2 * kt][1]);
            u[1] = pk_relu_bf16(h2c[2 * kt][2], h2c[2 * kt][3]);
            u[2] = pk_relu_bf16(h2c[2 * kt + 1][0], h2c[2 * kt + 1][1]);
            u[3] = pk_relu_bf16(h2c[2 * kt + 1][2], h2c[2 * kt + 1][3]);
            h2b[kt] = __builtin_bit_cast(bf16x8, u);
        }

        // ---- layer 3: two parallel 2-chains ----
        f32x4 za = __builtin_amdgcn_mfma_f32_16x16x32_bf16(w3f[0], h2b[0], b3r, 0, 0, 0);
        za = __builtin_amdgcn_mfma_f32_16x16x32_bf16(w3f[1], h2b[1], za, 0, 0, 0);
        f32x4 zb = __builtin_amdgcn_mfma_f32_16x16x32_bf16(
            w3f[2], h2b[2], (f32x4){0.f, 0.f, 0.f, 0.f}, 0, 0, 0);
        zb = __builtin_amdgcn_mfma_f32_16x16x32_bf16(w3f[3], h2b[3], zb, 0, 0, 0);

        // ---- V partial + X update (no cross-lane work in the loop) ----
#pragma unroll
        for (int r = 0; r < 4; ++r) {
            float z  = za[r] + zb[r];
            float wn = sqdt * e0[r];
            vacc = fmaf(z, wn, fmaf(0.01f * z, z, vacc));   // z*wn + dt/2*z^2
            x[r] = fmaf(x[r], 0.98f, wn);                   // (1-dt)*x + wn
        }

        e0 = e1; e1 = e2;
        t += dt;
    }

    // ---- V reduction across the 4 q-groups within each wave ----
    float part = vacc;
    part += __shfl_xor(part, 16);
    part += __shfl_xor(part, 32);

    // ---- combine the two time-halves (single end-of-kernel barrier) ----
    __shared__ float vpart[16];
    if (half == 0 && q == 0) vpart[n] = part;
    __syncthreads();
    if (half == 1) {
        *(f32x4*)&out[gr * D_ + q * 4] = x;                 // final X (step 50)
        if (q == 0) out[N_ * D_ + gr] = V0[gr] + vpart[n] + part;
    }
}

extern "C" void kernel_launch(void* const* d_in, const int* in_sizes, int n_in,
                              void* d_out, int out_size, void* d_ws, size_t ws_size,
                              hipStream_t stream)
{
    const float* X0 = (const float*)d_in[0];
    const float* V0 = (const float*)d_in[1];
    const float* Y  = (const float*)d_in[2];
    const float* nz = (const float*)d_in[3];
    const float* W1 = (const float*)d_in[4];
    const float* b1 = (const float*)d_in[5];
    const float* W2 = (const float*)d_in[6];
    const float* b2 = (const float*)d_in[7];
    const float* W3 = (const float*)d_in[8];
    const float* b3 = (const float*)d_in[9];
    float* out = (float*)d_out;

    sde_fused<<<N_ / 16, 128, 0, stream>>>(X0, V0, Y, nz, W1, b1, W2, b2, W3, b3, out);
}

// Round 4
// 149.125 us; speedup vs baseline: 1.6136x; 1.6136x over previous
//
#include <hip/hip_runtime.h>

typedef __bf16   bf16x8 __attribute__((ext_vector_type(8)));
typedef float    f32x4  __attribute__((ext_vector_type(4)));
typedef float    f32x2  __attribute__((ext_vector_type(2)));
typedef uint32_t u32x4  __attribute__((ext_vector_type(4)));

constexpr int N_ = 16384;
constexpr int D_ = 16;
constexpr int P_ = 8;
constexpr int H_ = 128;
constexpr int M_ = 50;

// prologue-only pack (round-half-up, matches prior passing weight quantization)
__device__ __forceinline__ uint32_t pk_bf16(float a, float b) {
    uint32_t ua = __builtin_bit_cast(uint32_t, a) + 0x8000u;
    uint32_t ub = __builtin_bit_cast(uint32_t, b) + 0x8000u;
    return __builtin_amdgcn_perm(ub, ua, 0x07060302u);   // low=a, high=b
}
// in-loop pack: single-instruction packed convert (RNE), gfx950
__device__ __forceinline__ uint32_t cvtpk(float a, float b) {
    uint32_t r;
    asm("v_cvt_pk_bf16_f32 %0, %1, %2" : "=v"(r) : "v"(a), "v"(b));
    return r;   // low=a, high=b
}
__device__ __forceinline__ uint32_t cvtpk_relu(float a, float b) {
    return cvtpk(fmaxf(a, 0.0f), fmaxf(b, 0.0f));
}

// R7: time-split (R6) made to FIT the 2-wave/SIMD 256-reg budget.
// R6 post-mortem: launch_bounds(128,2) caps unified V+A regs at 256; full
// resident network (~290) spilled -> 100 MB scratch writes, 155 us. Fix:
// keep only w2f (128 regs, 32 uses/step) in registers; w1f/w3f fragments and
// b2 live in LDS (12.6 KB/block, lane-contiguous ds_read_b128, conflict-free;
// b2 is a 16-lane broadcast read used directly as the L2 C-in). Ledger ~232.
// Zero in-loop barriers (weights are read-only after one prologue barrier);
// the two waves (time-halves 0-24 / 25-49) run unsynchronized and fill each
// other's MFMA/VALU latency bubbles. v_cvt_pk_bf16_f32 cuts pack VALU 5->3
// ops/word. One __syncthreads at the end combines V partials.
__global__ __launch_bounds__(128, 2)
void sde_fused(const float* __restrict__ X0,
               const float* __restrict__ V0,
               const float* __restrict__ Yobs,
               const float* __restrict__ noise,
               const float* __restrict__ W1, const float* __restrict__ b1,
               const float* __restrict__ W2, const float* __restrict__ b2,
               const float* __restrict__ W3, const float* __restrict__ b3,
               float* __restrict__ out)
{
    const int tid  = threadIdx.x;
    const int lane = tid & 63;
    const int half = tid >> 6;           // 0: steps 0..24, 1: steps 25..49
    const int n    = lane & 15;
    const int q    = lane >> 4;
    const int gr   = blockIdx.x * 16 + n;

    const float dt   = 0.02f;
    const float sqdt = 0.1414213562373095f;

    __shared__ bf16x8 w1lds[8][64];      // 8 KB: layer-1 A fragments per lane
    __shared__ bf16x8 w3lds[4][64];      // 4 KB: layer-3 A fragments per lane
    __shared__ float  b2lds[H_];         // 512 B
    __shared__ float  vpart[16];

    // ---- prologue: wave 0 stages the LDS-resident operands ----
    if (half == 0) {
#pragma unroll
        for (int ct = 0; ct < 8; ++ct) {
            u32x4 u;
            u[0] = pk_bf16(W1[(1 + q * 4 + 0) * H_ + ct * 16 + n],
                           W1[(1 + q * 4 + 1) * H_ + ct * 16 + n]);
            u[1] = pk_bf16(W1[(1 + q * 4 + 2) * H_ + ct * 16 + n],
                           W1[(1 + q * 4 + 3) * H_ + ct * 16 + n]);
            u[2] = pk_bf16(W1[(17 + q * 2 + 0) * H_ + ct * 16 + n],
                           W1[(17 + q * 2 + 1) * H_ + ct * 16 + n]);
            u[3] = (q == 0) ? pk_bf16(b1[ct * 16 + n], W1[ct * 16 + n]) : 0u;
            w1lds[ct][lane] = __builtin_bit_cast(bf16x8, u);
        }
#pragma unroll
        for (int kt = 0; kt < 4; ++kt) {
            u32x4 u;
#pragma unroll
            for (int w = 0; w < 4; ++w) {
                int h0 = (kt * 2 + (w >> 1)) * 16 + q * 4 + (w & 1) * 2;
                u[w] = pk_bf16(W3[h0 * D_ + n], W3[(h0 + 1) * D_ + n]);
            }
            w3lds[kt][lane] = __builtin_bit_cast(bf16x8, u);
        }
        if (lane < 32) *(f32x4*)&b2lds[lane * 4] = *(const f32x4*)&b2[lane * 4];
    }

    // ---- w2f: register-resident in BOTH waves (the only big resident set) ----
    bf16x8 w2f[8][4];
#pragma unroll
    for (int ct = 0; ct < 8; ++ct)
#pragma unroll
        for (int kt = 0; kt < 4; ++kt) {
            u32x4 u;
#pragma unroll
            for (int w = 0; w < 4; ++w) {
                int h0 = (kt * 2 + (w >> 1)) * 16 + q * 4 + (w & 1) * 2;
                u[w] = pk_bf16(W2[h0 * H_ + ct * 16 + n],
                               W2[(h0 + 1) * H_ + ct * 16 + n]);
            }
            w2f[ct][kt] = __builtin_bit_cast(bf16x8, u);
        }

    f32x4 b3r = *(const f32x4*)&b3[q * 4];

    __syncthreads();   // one-time: LDS weights ready

    // ---- state ----
    f32x4 x = *(const f32x4*)&X0[gr * D_ + q * 4];
    f32x2 y2 = *(const f32x2*)&Yobs[gr * P_ + q * 2];
    const uint32_t yw = pk_bf16(y2[0], y2[1]);

    const float* npb = noise + (size_t)gr * D_ + q * 4;

    // ---- wave 1: bit-exact replay of the X recurrence through steps 0..24 ----
    if (half == 1) {
#pragma unroll 5
        for (int m = 0; m < 25; ++m) {
            f32x4 e = *(const f32x4*)(npb + (size_t)m * N_ * D_);
#pragma unroll
            for (int r = 0; r < 4; ++r)
                x[r] = fmaf(x[r], 0.98f, sqdt * e[r]);
        }
    }

    const int s0 = half * 25;
    float t = half ? 0.5f : 0.0f;        // 25*dt == 0.5 (R6-verified handoff)

    f32x4 e0 = *(const f32x4*)(npb + (size_t)s0 * N_ * D_);
    f32x4 e1 = *(const f32x4*)(npb + (size_t)(s0 + 1) * N_ * D_);
    float vacc = 0.0f;

#pragma unroll 1
    for (int i = 0; i < 25; ++i) {
        const int m  = s0 + i;
        const int mp = (m + 2 < M_) ? (m + 2) : (M_ - 1);
        f32x4 e2 = *(const f32x4*)(npb + (size_t)mp * N_ * D_);

        // ---- layer 1 B fragment: [X(4) | Y(2) | one | t] ----
        u32x4 au;
        au[0] = cvtpk(x[0], x[1]);
        au[1] = cvtpk(x[2], x[3]);
        au[2] = yw;
        au[3] = (q == 0) ? cvtpk(1.0f, t) : 0u;
        bf16x8 a0 = __builtin_bit_cast(bf16x8, au);

        // ---- layer 1: stream w1 fragments from LDS, pack pairs ----
        bf16x8 h1b[4];
#pragma unroll
        for (int kt = 0; kt < 4; ++kt) {
            bf16x8 wa = w1lds[2 * kt][lane];
            bf16x8 wb = w1lds[2 * kt + 1][lane];
            f32x4 ha = __builtin_amdgcn_mfma_f32_16x16x32_bf16(
                wa, a0, (f32x4){0.f, 0.f, 0.f, 0.f}, 0, 0, 0);
            f32x4 hb = __builtin_amdgcn_mfma_f32_16x16x32_bf16(
                wb, a0, (f32x4){0.f, 0.f, 0.f, 0.f}, 0, 0, 0);
            u32x4 u;
            u[0] = cvtpk_relu(ha[0], ha[1]);
            u[1] = cvtpk_relu(ha[2], ha[3]);
            u[2] = cvtpk_relu(hb[0], hb[1]);
            u[3] = cvtpk_relu(hb[2], hb[3]);
            h1b[kt] = __builtin_bit_cast(bf16x8, u);
        }

        // ---- layer 2 batch 1: ct 0..3 (C-in = b2 broadcast from LDS) ----
        bf16x8 h2b[4];
        {
            f32x4 h2c[4];
#pragma unroll
            for (int cc = 0; cc < 4; ++cc) {
                f32x4 c = *(const f32x4*)&b2lds[cc * 16 + q * 4];
#pragma unroll
                for (int kt = 0; kt < 4; ++kt)
                    c = __builtin_amdgcn_mfma_f32_16x16x32_bf16(
                        w2f[cc][kt], h1b[kt], c, 0, 0, 0);
                h2c[cc] = c;
            }
#pragma unroll
            for (int j = 0; j < 2; ++j) {
                u32x4 u;
                u[0] = cvtpk_relu(h2c[2 * j][0], h2c[2 * j][1]);
                u[1] = cvtpk_relu(h2c[2 * j][2], h2c[2 * j][3]);
                u[2] = cvtpk_relu(h2c[2 * j + 1][0], h2c[2 * j + 1][1]);
                u[3] = cvtpk_relu(h2c[2 * j + 1][2], h2c[2 * j + 1][3]);
                h2b[j] = __builtin_bit_cast(bf16x8, u);
            }
        }
        // ---- layer 2 batch 2: ct 4..7 ----
        {
            f32x4 h2c[4];
#pragma unroll
            for (int cc = 0; cc < 4; ++cc) {
                f32x4 c = *(const f32x4*)&b2lds[(cc + 4) * 16 + q * 4];
#pragma unroll
                for (int kt = 0; kt < 4; ++kt)
                    c = __builtin_amdgcn_mfma_f32_16x16x32_bf16(
                        w2f[cc + 4][kt], h1b[kt], c, 0, 0, 0);
                h2c[cc] = c;
            }
#pragma unroll
            for (int j = 0; j < 2; ++j) {
                u32x4 u;
                u[0] = cvtpk_relu(h2c[2 * j][0], h2c[2 * j][1]);
                u[1] = cvtpk_relu(h2c[2 * j][2], h2c[2 * j][3]);
                u[2] = cvtpk_relu(h2c[2 * j + 1][0], h2c[2 * j + 1][1]);
                u[3] = cvtpk_relu(h2c[2 * j + 1][2], h2c[2 * j + 1][3]);
                h2b[2 + j] = __builtin_bit_cast(bf16x8, u);
            }
        }

        // ---- layer 3: stream w3 fragments; latency hides under next step's L1 ----
        bf16x8 w3a = w3lds[0][lane];
        bf16x8 w3b = w3lds[1][lane];
        f32x4 za = __builtin_amdgcn_mfma_f32_16x16x32_bf16(w3a, h2b[0], b3r, 0, 0, 0);
        za = __builtin_amdgcn_mfma_f32_16x16x32_bf16(w3b, h2b[1], za, 0, 0, 0);
        bf16x8 w3c = w3lds[2][lane];
        bf16x8 w3d = w3lds[3][lane];
        f32x4 zb = __builtin_amdgcn_mfma_f32_16x16x32_bf16(
            w3c, h2b[2], (f32x4){0.f, 0.f, 0.f, 0.f}, 0, 0, 0);
        zb = __builtin_amdgcn_mfma_f32_16x16x32_bf16(w3d, h2b[3], zb, 0, 0, 0);

        // ---- V partial + X update ----
#pragma unroll
        for (int r = 0; r < 4; ++r) {
            float z  = za[r] + zb[r];
            float wn = sqdt * e0[r];
            vacc = fmaf(z, wn, fmaf(0.01f * z, z, vacc));   // z*wn + dt/2*z^2
            x[r] = fmaf(x[r], 0.98f, wn);                   // (1-dt)*x + wn
        }

        e0 = e1; e1 = e2;
        t += dt;
    }

    // ---- V reduction across the 4 q-groups within each wave ----
    float part = vacc;
    part += __shfl_xor(part, 16);
    part += __shfl_xor(part, 32);

    // ---- combine the two time-halves (single end-of-kernel barrier) ----
    if (half == 0 && q == 0) vpart[n] = part;
    __syncthreads();
    if (half == 1) {
        *(f32x4*)&out[gr * D_ + q * 4] = x;                 // final X (step 50)
        if (q == 0) out[N_ * D_ + gr] = V0[gr] + vpart[n] + part;
    }
}

extern "C" void kernel_launch(void* const* d_in, const int* in_sizes, int n_in,
                              void* d_out, int out_size, void* d_ws, size_t ws_size,
                              hipStream_t stream)
{
    const float* X0 = (const float*)d_in[0];
    const float* V0 = (const float*)d_in[1];
    const float* Y  = (const float*)d_in[2];
    const float* nz = (const float*)d_in[3];
    const float* W1 = (const float*)d_in[4];
    const float* b1 = (const float*)d_in[5];
    const float* W2 = (const float*)d_in[6];
    const float* b2 = (const float*)d_in[7];
    const float* W3 = (const float*)d_in[8];
    const float* b3 = (const float*)d_in[9];
    float* out = (float*)d_out;

    sde_fused<<<N_ / 16, 128, 0, stream>>>(X0, V0, Y, nz, W1, b1, W2, b2, W3, b3, out);
}

// Round 5
// 139.255 us; speedup vs baseline: 1.7279x; 1.0709x over previous
//
#include <hip/hip_runtime.h>

typedef __bf16   bf16x8 __attribute__((ext_vector_type(8)));
typedef float    f32x4  __attribute__((ext_vector_type(4)));
typedef float    f32x2  __attribute__((ext_vector_type(2)));
typedef uint32_t u32x4  __attribute__((ext_vector_type(4)));

constexpr int N_ = 16384;
constexpr int D_ = 16;
constexpr int P_ = 8;
constexpr int H_ = 128;
constexpr int M_ = 50;

// prologue-only pack (round-half-up; matches the weight quantization of all
// passing rounds)
__device__ __forceinline__ uint32_t pk_bf16(float a, float b) {
    uint32_t ua = __builtin_bit_cast(uint32_t, a) + 0x8000u;
    uint32_t ub = __builtin_bit_cast(uint32_t, b) + 0x8000u;
    return __builtin_amdgcn_perm(ub, ua, 0x07060302u);   // low=a, high=b
}
// in-loop pack: single-instruction packed convert (RNE) — numerics validated
// in R7 (passed, absmax unchanged at 0.0625)
__device__ __forceinline__ uint32_t cvtpk(float a, float b) {
    uint32_t r;
    asm("v_cvt_pk_bf16_f32 %0, %1, %2" : "=v"(r) : "v"(a), "v"(b));
    return r;
}
__device__ __forceinline__ uint32_t cvtpk_relu(float a, float b) {
    return cvtpk(fmaxf(a, 0.0f), fmaxf(b, 0.0f));
}

// R8 = R0 base (57us, 1 wave/SIMD, zero spill) + two latency levers:
//  (a) v_cvt_pk_bf16_f32 for all in-loop packs (3->1 VALU per word, ~70
//      ops/step saved; numerics proven in R7).
//  (b) 2-deep CROSS-STEP software pipeline: X_{m+1} depends only on X_m and
//      noise (never on Z), so step m+1's x-update + a0-pack + all 8 layer-1
//      MFMAs are issued DURING step m's layer-2/3 — always-available
//      independent work to fill the serial-chain stalls. Static 2-state
//      (named h1b / h1cn arrays, no runtime indexing — rule #20).
// R6/R7 lesson baked in: the full network needs ~290+ unified regs -> only
// fits the 1-wave/SIMD 512-reg budget; 2 waves/SIMD spills (100MB/18MB
// scratch). So: 64-thread blocks, launch_bounds(64,1), no LDS, no barriers.
__global__ __launch_bounds__(64, 1)
void sde_fused(const float* __restrict__ X0,
               const float* __restrict__ V0,
               const float* __restrict__ Yobs,
               const float* __restrict__ noise,
               const float* __restrict__ W1, const float* __restrict__ b1,
               const float* __restrict__ W2, const float* __restrict__ b2,
               const float* __restrict__ W3, const float* __restrict__ b3,
               float* __restrict__ out)
{
    const int lane = threadIdx.x;
    const int n    = lane & 15;
    const int q    = lane >> 4;
    const int gr   = blockIdx.x * 16 + n;

    const float dt   = 0.02f;
    const float sqdt = 0.1414213562373095f;

    // ---- weight fragments, A-operand layout A[m=lane&15][k=q*8+j] ----
    bf16x8 w1f[8];
#pragma unroll
    for (int ct = 0; ct < 8; ++ct) {
        u32x4 u;
        u[0] = pk_bf16(W1[(1 + q * 4 + 0) * H_ + ct * 16 + n],
                       W1[(1 + q * 4 + 1) * H_ + ct * 16 + n]);
        u[1] = pk_bf16(W1[(1 + q * 4 + 2) * H_ + ct * 16 + n],
                       W1[(1 + q * 4 + 3) * H_ + ct * 16 + n]);
        u[2] = pk_bf16(W1[(17 + q * 2 + 0) * H_ + ct * 16 + n],
                       W1[(17 + q * 2 + 1) * H_ + ct * 16 + n]);
        u[3] = (q == 0) ? pk_bf16(b1[ct * 16 + n], W1[ct * 16 + n]) : 0u;
        w1f[ct] = __builtin_bit_cast(bf16x8, u);
    }
    bf16x8 w2f[8][4];
#pragma unroll
    for (int ct = 0; ct < 8; ++ct)
#pragma unroll
        for (int kt = 0; kt < 4; ++kt) {
            u32x4 u;
#pragma unroll
            for (int w = 0; w < 4; ++w) {
                int h0 = (kt * 2 + (w >> 1)) * 16 + q * 4 + (w & 1) * 2;
                u[w] = pk_bf16(W2[h0 * H_ + ct * 16 + n],
                               W2[(h0 + 1) * H_ + ct * 16 + n]);
            }
            w2f[ct][kt] = __builtin_bit_cast(bf16x8, u);
        }
    bf16x8 w3f[4];
#pragma unroll
    for (int kt = 0; kt < 4; ++kt) {
        u32x4 u;
#pragma unroll
        for (int w = 0; w < 4; ++w) {
            int h0 = (kt * 2 + (w >> 1)) * 16 + q * 4 + (w & 1) * 2;
            u[w] = pk_bf16(W3[h0 * D_ + n], W3[(h0 + 1) * D_ + n]);
        }
        w3f[kt] = __builtin_bit_cast(bf16x8, u);
    }
    f32x4 b2r[8];
#pragma unroll
    for (int ct = 0; ct < 8; ++ct)
#pragma unroll
        for (int r = 0; r < 4; ++r) b2r[ct][r] = b2[ct * 16 + q * 4 + r];
    f32x4 b3r;
#pragma unroll
    for (int r = 0; r < 4; ++r) b3r[r] = b3[q * 4 + r];

    // ---- state ----
    f32x4 x = *(const f32x4*)&X0[gr * D_ + q * 4];
    f32x2 y2 = *(const f32x2*)&Yobs[gr * P_ + q * 2];
    const uint32_t yw = pk_bf16(y2[0], y2[1]);   // constant word2 of a0

    const float* npb = noise + (size_t)gr * D_ + q * 4;
    f32x4 e0 = *(const f32x4*)npb;
    f32x4 e1 = *(const f32x4*)(npb + (size_t)N_ * D_);
    float t = 0.0f;
    float vacc = 0.0f;

    // ---- pipeline prologue: layer 1 of step 0 ----
    bf16x8 h1b[4];
    {
        u32x4 au;
        au[0] = cvtpk(x[0], x[1]);
        au[1] = cvtpk(x[2], x[3]);
        au[2] = yw;
        au[3] = (q == 0) ? cvtpk(1.0f, 0.0f) : 0u;
        bf16x8 a0 = __builtin_bit_cast(bf16x8, au);
        f32x4 h1c[8];
#pragma unroll
        for (int ct = 0; ct < 8; ++ct)
            h1c[ct] = __builtin_amdgcn_mfma_f32_16x16x32_bf16(
                w1f[ct], a0, (f32x4){0.f, 0.f, 0.f, 0.f}, 0, 0, 0);
#pragma unroll
        for (int kt = 0; kt < 4; ++kt) {
            u32x4 u;
            u[0] = cvtpk_relu(h1c[2 * kt][0], h1c[2 * kt][1]);
            u[1] = cvtpk_relu(h1c[2 * kt][2], h1c[2 * kt][3]);
            u[2] = cvtpk_relu(h1c[2 * kt + 1][0], h1c[2 * kt + 1][1]);
            u[3] = cvtpk_relu(h1c[2 * kt + 1][2], h1c[2 * kt + 1][3]);
            h1b[kt] = __builtin_bit_cast(bf16x8, u);
        }
    }

    // ---- steady state: step m's L2/L3/V overlapped with step m+1's x/a0/L1 ----
#pragma unroll 1
    for (int m = 0; m < M_ - 1; ++m) {
        const int mp = (m + 2 < M_) ? (m + 2) : (M_ - 1);
        f32x4 e2 = *(const f32x4*)(npb + (size_t)mp * N_ * D_);

        // next step's X (depends only on x, e0 — available now)
        f32x4 xn;
#pragma unroll
        for (int r = 0; r < 4; ++r) xn[r] = fmaf(x[r], 0.98f, sqdt * e0[r]);

        // next step's layer-1 B fragment + 8 independent MFMAs
        u32x4 aun;
        aun[0] = cvtpk(xn[0], xn[1]);
        aun[1] = cvtpk(xn[2], xn[3]);
        aun[2] = yw;
        aun[3] = (q == 0) ? cvtpk(1.0f, t + dt) : 0u;
        bf16x8 a0n = __builtin_bit_cast(bf16x8, aun);
        f32x4 h1cn[8];
#pragma unroll
        for (int ct = 0; ct < 8; ++ct)
            h1cn[ct] = __builtin_amdgcn_mfma_f32_16x16x32_bf16(
                w1f[ct], a0n, (f32x4){0.f, 0.f, 0.f, 0.f}, 0, 0, 0);

        // current step's layer 2: 8 independent chains of 4
        f32x4 h2c[8];
#pragma unroll
        for (int ct = 0; ct < 8; ++ct) {
            f32x4 c = b2r[ct];
#pragma unroll
            for (int kt = 0; kt < 4; ++kt)
                c = __builtin_amdgcn_mfma_f32_16x16x32_bf16(
                    w2f[ct][kt], h1b[kt], c, 0, 0, 0);
            h2c[ct] = c;
        }
        bf16x8 h2b[4];
#pragma unroll
        for (int kt = 0; kt < 4; ++kt) {
            u32x4 u;
            u[0] = cvtpk_relu(h2c[2 * kt][0], h2c[2 * kt][1]);
            u[1] = cvtpk_relu(h2c[2 * kt][2], h2c[2 * kt][3]);
            u[2] = cvtpk_relu(h2c[2 * kt + 1][0], h2c[2 * kt + 1][1]);
            u[3] = cvtpk_relu(h2c[2 * kt + 1][2], h2c[2 * kt + 1][3]);
            h2b[kt] = __builtin_bit_cast(bf16x8, u);
        }

        // current step's layer 3
        f32x4 za = __builtin_amdgcn_mfma_f32_16x16x32_bf16(w3f[0], h2b[0], b3r, 0, 0, 0);
        za = __builtin_amdgcn_mfma_f32_16x16x32_bf16(w3f[1], h2b[1], za, 0, 0, 0);
        f32x4 zb = __builtin_amdgcn_mfma_f32_16x16x32_bf16(
            w3f[2], h2b[2], (f32x4){0.f, 0.f, 0.f, 0.f}, 0, 0, 0);
        zb = __builtin_amdgcn_mfma_f32_16x16x32_bf16(w3f[3], h2b[3], zb, 0, 0, 0);

        // retire next step's layer 1 (placed late: ~36 MFMAs of latency cover)
#pragma unroll
        for (int kt = 0; kt < 4; ++kt) {
            u32x4 u;
            u[0] = cvtpk_relu(h1cn[2 * kt][0], h1cn[2 * kt][1]);
            u[1] = cvtpk_relu(h1cn[2 * kt][2], h1cn[2 * kt][3]);
            u[2] = cvtpk_relu(h1cn[2 * kt + 1][0], h1cn[2 * kt + 1][1]);
            u[3] = cvtpk_relu(h1cn[2 * kt + 1][2], h1cn[2 * kt + 1][3]);
            h1b[kt] = __builtin_bit_cast(bf16x8, u);
        }

        // current step's V partial; advance state
#pragma unroll
        for (int r = 0; r < 4; ++r) {
            float z  = za[r] + zb[r];
            float wn = sqdt * e0[r];
            vacc = fmaf(z, wn, fmaf(0.01f * z, z, vacc));   // z*wn + dt/2*z^2
        }
        x = xn;
        e0 = e1; e1 = e2;
        t += dt;
    }

    // ---- epilogue: step M-1 (h1b/x/e0/t already correspond to it) ----
    {
        f32x4 h2c[8];
#pragma unroll
        for (int ct = 0; ct < 8; ++ct) {
            f32x4 c = b2r[ct];
#pragma unroll
            for (int kt = 0; kt < 4; ++kt)
                c = __builtin_amdgcn_mfma_f32_16x16x32_bf16(
                    w2f[ct][kt], h1b[kt], c, 0, 0, 0);
            h2c[ct] = c;
        }
        bf16x8 h2b[4];
#pragma unroll
        for (int kt = 0; kt < 4; ++kt) {
            u32x4 u;
            u[0] = cvtpk_relu(h2c[2 * kt][0], h2c[2 * kt][1]);
            u[1] = cvtpk_relu(h2c[2 * kt][2], h2c[2 * kt][3]);
            u[2] = cvtpk_relu(h2c[2 * kt + 1][0], h2c[2 * kt + 1][1]);
            u[3] = cvtpk_relu(h2c[2 * kt + 1][2], h2c[2 * kt + 1][3]);
            h2b[kt] = __builtin_bit_cast(bf16x8, u);
        }
        f32x4 za = __builtin_amdgcn_mfma_f32_16x16x32_bf16(w3f[0], h2b[0], b3r, 0, 0, 0);
        za = __builtin_amdgcn_mfma_f32_16x16x32_bf16(w3f[1], h2b[1], za, 0, 0, 0);
        f32x4 zb = __builtin_amdgcn_mfma_f32_16x16x32_bf16(
            w3f[2], h2b[2], (f32x4){0.f, 0.f, 0.f, 0.f}, 0, 0, 0);
        zb = __builtin_amdgcn_mfma_f32_16x16x32_bf16(w3f[3], h2b[3], zb, 0, 0, 0);
#pragma unroll
        for (int r = 0; r < 4; ++r) {
            float z  = za[r] + zb[r];
            float wn = sqdt * e0[r];
            vacc = fmaf(z, wn, fmaf(0.01f * z, z, vacc));
            x[r] = fmaf(x[r], 0.98f, wn);                   // final X (step 50)
        }
    }

    // ---- final V reduction across the 4 q-groups ----
    float part = vacc;
    part += __shfl_xor(part, 16);
    part += __shfl_xor(part, 32);
    float v = V0[gr] + part;

    *(f32x4*)&out[gr * D_ + q * 4] = x;
    if (q == 0) out[N_ * D_ + gr] = v;
}

extern "C" void kernel_launch(void* const* d_in, const int* in_sizes, int n_in,
                              void* d_out, int out_size, void* d_ws, size_t ws_size,
                              hipStream_t stream)
{
    const float* X0 = (const float*)d_in[0];
    const float* V0 = (const float*)d_in[1];
    const float* Y  = (const float*)d_in[2];
    const float* nz = (const float*)d_in[3];
    const float* W1 = (const float*)d_in[4];
    const float* b1 = (const float*)d_in[5];
    const float* W2 = (const float*)d_in[6];
    const float* b2 = (const float*)d_in[7];
    const float* W3 = (const float*)d_in[8];
    const float* b3 = (const float*)d_in[9];
    float* out = (float*)d_out;

    sde_fused<<<N_ / 16, 64, 0, stream>>>(X0, V0, Y, nz, W1, b1, W2, b2, W3, b3, out);
}